// Round 6
// baseline (1600.147 us; speedup 1.0000x reference)
//
#include <hip/hip_runtime.h>
#include <hip/hip_bf16.h>

// ---------------------------------------------------------------------------
// EncoderGAE: 8-layer GCN encoder on MI355X.
// R12: (a) gemm_bn reverted to R9 (measured-best: 64x256 tile, LDS-staged,
//      ~32us/layer; R10/R11 direct-reg variants were latency-stalled).
//      (b) sliced agg retry with the R7 failure FIXED: edges2 is streamed with
//      NON-TEMPORAL loads and Y written with NT stores, so each XCD's 4MB L2
//      keeps its 3.2MB X-slice resident (R7's slice was evicted by the 6.4MB
//      edge stream -> zero residency, FETCH unchanged). slice = bid&7 pins
//      slices to XCDs under round-robin dispatch. Fused BN stats via
//      shfl-reduce + 64 atomics/block.
// ---------------------------------------------------------------------------

#define NN 50000
#define NE 800000
#define DD 256

typedef __attribute__((ext_vector_type(8))) short short8;
typedef __attribute__((ext_vector_type(4))) float f32x4;

static __device__ __forceinline__ ushort f2bf(float f) {
    unsigned u = __float_as_uint(f);
    unsigned r = (u + 0x7fffu + ((u >> 16) & 1u)) >> 16;   // RNE
    return (ushort)r;
}
static __device__ __forceinline__ float bf_lo(unsigned x) {
    return __uint_as_float(x << 16);
}
static __device__ __forceinline__ float bf_hi(unsigned x) {
    return __uint_as_float(x & 0xffff0000u);
}

// ------------------------- gcn_norm + CSR build ----------------------------
__global__ void edge_stat_kernel(const int* __restrict__ dst,
                                 const float* __restrict__ ew,
                                 unsigned long long* __restrict__ cells,
                                 int* __restrict__ rank) {
    int e = blockIdx.x * 256 + threadIdx.x;
    if (e < NE) {
        unsigned long long inc =
            (1ULL << 40) | (unsigned long long)(unsigned)rintf(ew[e] * 16777216.0f);
        unsigned long long old = atomicAdd(&cells[dst[e]], inc);
        rank[e] = (int)(old >> 40);
    }
}

__global__ void deg_finish_kernel(const unsigned long long* __restrict__ cells,
                                  int* __restrict__ cnt,
                                  float* __restrict__ dinv) {
    int i = blockIdx.x * 256 + threadIdx.x;
    if (i < NN) {
        unsigned long long c = cells[i];
        cnt[i] = (int)(c >> 40);
        float deg = 1.0f + (float)(c & ((1ULL << 40) - 1)) * (1.0f / 16777216.0f);
        dinv[i] = rsqrtf(deg);  // deg >= 1 always (self-loop)
    }
}

__global__ void scan_kernel(const int* __restrict__ cnt, int* __restrict__ rowptr, int n) {
    __shared__ int wsum[16];
    __shared__ int carry_s;
    int tid = threadIdx.x;
    int lane = tid & 63;
    int wid = tid >> 6;
    if (tid == 0) carry_s = 0;
    __syncthreads();
    for (int base = 0; base < n; base += 1024) {
        int i = base + tid;
        int v = (i < n) ? cnt[i] : 0;
        int x = v;
        #pragma unroll
        for (int o = 1; o < 64; o <<= 1) {
            int y = __shfl_up(x, o, 64);
            if (lane >= o) x += y;
        }
        if (lane == 63) wsum[wid] = x;
        __syncthreads();
        if (wid == 0) {
            int w = (lane < 16) ? wsum[lane] : 0;
            #pragma unroll
            for (int o = 1; o < 16; o <<= 1) {
                int y = __shfl_up(w, o, 64);
                if (lane >= o) w += y;
            }
            if (lane < 16) wsum[lane] = w;
        }
        __syncthreads();
        int wexcl = (wid > 0) ? wsum[wid - 1] : 0;
        int incl = x + wexcl;
        int c = carry_s;
        if (i < n) rowptr[i] = c + incl - v;
        __syncthreads();
        if (tid == 1023) carry_s = c + wsum[15];
        __syncthreads();
    }
    if (tid == 0) rowptr[n] = carry_s;
}

// Atomic-free fill: position = rowptr[dst] + rank; one 8B write per edge.
__global__ void fill_kernel(const int* __restrict__ src,
                            const int* __restrict__ dst,
                            const float* __restrict__ ew,
                            const float* __restrict__ dinv,
                            const int* __restrict__ rank,
                            const int* __restrict__ rowptr,
                            int2* __restrict__ edges2) {
    int e = blockIdx.x * 256 + threadIdx.x;
    if (e < NE) {
        int s = src[e], d = dst[e];
        float nrm = dinv[s] * ew[e] * dinv[d];
        int p = rowptr[d] + rank[e];
        edges2[p] = make_int2(s, __float_as_int(nrm));
    }
}

// ---------------------- weight transpose + bf16 cvt ------------------------
__global__ void wcvt_kernel(const float* __restrict__ Wm,
                            const float* __restrict__ Wl,
                            ushort* __restrict__ Bt) {
    int idx = blockIdx.x * 256 + threadIdx.x;
    if (idx >= 7 * 65536) return;
    int l = idx >> 16;
    int nk = idx & 65535;
    int n = nk >> 8, k = nk & 255;
    const float* W = (l < 6) ? (Wm + (size_t)l * 65536) : Wl;
    Bt[idx] = f2bf(W[k * 256 + n]);
}

// ------------------- layer-0: aggregate raw h (N x 6) ----------------------
// agg(h @ W1) == agg(h) @ W1 by row-linearity; h is 1.2 MB -> L2-resident.
__global__ void agg6_kernel(const float* __restrict__ h,
                            const int* __restrict__ rowptr,
                            const int2* __restrict__ edges2,
                            const float* __restrict__ dinv,
                            float* __restrict__ Hagg) {
    int node = blockIdx.x * 256 + threadIdx.x;
    if (node >= NN) return;
    float di = dinv[node];
    float w0 = di * di;
    const float2* hp = (const float2*)(h + (size_t)node * 6);
    float2 v0 = hp[0], v1 = hp[1], v2 = hp[2];
    float a0 = w0 * v0.x, a1 = w0 * v0.y, a2 = w0 * v1.x;
    float a3 = w0 * v1.y, a4 = w0 * v2.x, a5 = w0 * v2.y;
    int j = rowptr[node], jend = rowptr[node + 1];
    for (; j + 1 < jend; j += 2) {
        int2 e0 = edges2[j], e1 = edges2[j + 1];
        const float2* p0 = (const float2*)(h + (size_t)e0.x * 6);
        const float2* p1 = (const float2*)(h + (size_t)e1.x * 6);
        float2 x0 = p0[0], x1 = p0[1], x2 = p0[2];
        float2 y0 = p1[0], y1 = p1[1], y2 = p1[2];
        float t0 = __int_as_float(e0.y);
        float t1 = __int_as_float(e1.y);
        a0 = fmaf(t0, x0.x, a0); a1 = fmaf(t0, x0.y, a1);
        a2 = fmaf(t0, x1.x, a2); a3 = fmaf(t0, x1.y, a3);
        a4 = fmaf(t0, x2.x, a4); a5 = fmaf(t0, x2.y, a5);
        a0 = fmaf(t1, y0.x, a0); a1 = fmaf(t1, y0.y, a1);
        a2 = fmaf(t1, y1.x, a2); a3 = fmaf(t1, y1.y, a3);
        a4 = fmaf(t1, y2.x, a4); a5 = fmaf(t1, y2.y, a5);
    }
    if (j < jend) {
        int2 e = edges2[j];
        const float2* p = (const float2*)(h + (size_t)e.x * 6);
        float2 x0 = p[0], x1 = p[1], x2 = p[2];
        float t = __int_as_float(e.y);
        a0 = fmaf(t, x0.x, a0); a1 = fmaf(t, x0.y, a1);
        a2 = fmaf(t, x1.x, a2); a3 = fmaf(t, x1.y, a3);
        a4 = fmaf(t, x2.x, a4); a5 = fmaf(t, x2.y, a5);
    }
    float2* op = (float2*)(Hagg + (size_t)node * 6);
    op[0] = make_float2(a0, a1);
    op[1] = make_float2(a2, a3);
    op[2] = make_float2(a4, a5);
}

// Layer-0 GEMM: Yb[N,256] = bf16(Hagg[N,6] @ W1[6,256] + b1), fp32 math.
// 8 nodes per block; W1 column + bias held in registers.
__global__ void gemm0_kernel(const float* __restrict__ Hagg,
                             const float* __restrict__ W1,
                             const float* __restrict__ b1,
                             ushort* __restrict__ Yb) {
    int f = threadIdx.x;
    float w0 = W1[f],        w1 = W1[256 + f],  w2 = W1[512 + f];
    float w3 = W1[768 + f],  w4 = W1[1024 + f], w5 = W1[1280 + f];
    float bb = b1[f];
    int n0 = blockIdx.x * 8;
    #pragma unroll
    for (int t = 0; t < 8; ++t) {
        int i = n0 + t;
        const float2* hp = (const float2*)(Hagg + (size_t)i * 6);
        float2 h0 = hp[0], h1 = hp[1], h2 = hp[2];
        float s = bb;
        s = fmaf(h0.x, w0, s); s = fmaf(h0.y, w1, s);
        s = fmaf(h1.x, w2, s); s = fmaf(h1.y, w3, s);
        s = fmaf(h2.x, w4, s); s = fmaf(h2.y, w5, s);
        Yb[(size_t)i * 256 + f] = f2bf(s);
    }
}

// ---------------- MFMA bf16 GEMM with fused BN+leakyReLU on A --------------
// R9 version (measured best). C[M,256] = leaky(BN(Yb)) @ Bt^T. Tile 64x256,
// BK=32, 4 waves each 64x64. Yb read + BN transform once per row. A and B
// staged in padded LDS ([.][40] -> 80B stride, conflict-free ds_read_b128).
__launch_bounds__(256)
__global__ void gemm_bn_kernel(const ushort* __restrict__ Yb,
                               const ushort* __restrict__ Bt,
                               const float* __restrict__ scsh,
                               ushort* __restrict__ C, int M) {
    __shared__ __align__(16) ushort As[64][40];
    __shared__ __align__(16) ushort Bs[256][40];
    __shared__ float sc_s[256], sh_s[256];
    int tid = threadIdx.x;
    sc_s[tid] = scsh[tid];
    sh_s[tid] = scsh[256 + tid];
    int lane = tid & 63, wc = tid >> 6;      // wave = col quarter
    int lm = lane & 15, kq = lane >> 4;
    int row0 = blockIdx.x * 64;
    int arow = tid >> 2;                     // 0..63  (A staging row)
    int ah = (tid & 3) * 8;                  // A k-offset 0/8/16/24
    int bsub = tid >> 2;                     // 0..63  (B staging row within group)
    int bh = (tid & 3) * 8;                  // B k-offset

    f32x4 acc[4][4] = {};
    __syncthreads();  // sc_s/sh_s visible

    for (int k0 = 0; k0 < 256; k0 += 32) {
        // --- stage A: bf16 Yb -> BN -> leaky -> bf16, 8 elems/thread ---
        {
            int grow = row0 + arow;
            uint4 p = make_uint4(0, 0, 0, 0);
            if (grow < M) p = *(const uint4*)(Yb + (size_t)grow * 256 + k0 + ah);
            uint in[4] = {p.x, p.y, p.z, p.w};
            uint packed[4];
            #pragma unroll
            for (int t = 0; t < 4; ++t) {
                int cb = k0 + ah + t * 2;
                float y0 = bf_lo(in[t]);
                float y1 = bf_hi(in[t]);
                float o0 = fmaf(y0, sc_s[cb + 0], sh_s[cb + 0]);
                float o1 = fmaf(y1, sc_s[cb + 1], sh_s[cb + 1]);
                o0 = fmaxf(o0, 0.01f * o0);   // leaky(x) = max(x, 0.01x)
                o1 = fmaxf(o1, 0.01f * o1);
                packed[t] = (uint)f2bf(o0) | ((uint)f2bf(o1) << 16);
            }
            *(uint4*)&As[arow][ah] = make_uint4(packed[0], packed[1], packed[2], packed[3]);
        }
        // --- stage B: 256 rows x 32 k, 4 coalesced passes of 64 rows ---
        #pragma unroll
        for (int rr = 0; rr < 4; ++rr) {
            int brow = rr * 64 + bsub;
            uint4 bp = *(const uint4*)(Bt + (size_t)brow * 256 + k0 + bh);
            *(uint4*)&Bs[brow][bh] = bp;
        }
        __syncthreads();
        short8 af[4], bfj[4];
        #pragma unroll
        for (int i = 0; i < 4; ++i)
            af[i] = *(const short8*)&As[i * 16 + lm][kq * 8];
        #pragma unroll
        for (int j = 0; j < 4; ++j)
            bfj[j] = *(const short8*)&Bs[wc * 64 + j * 16 + lm][kq * 8];
        #pragma unroll
        for (int i = 0; i < 4; ++i)
            #pragma unroll
            for (int j = 0; j < 4; ++j)
                acc[i][j] = __builtin_amdgcn_mfma_f32_16x16x32_bf16(
                    af[i], bfj[j], acc[i][j], 0, 0, 0);
        __syncthreads();
    }

    // Epilogue: C/D layout col=lane&15, row=(lane>>4)*4+reg
    #pragma unroll
    for (int i = 0; i < 4; ++i) {
        #pragma unroll
        for (int j = 0; j < 4; ++j) {
            int col = wc * 64 + j * 16 + lm;
            #pragma unroll
            for (int r = 0; r < 4; ++r) {
                int grow = row0 + i * 16 + kq * 4 + r;
                if (grow < M) C[(size_t)grow * 256 + col] = f2bf(acc[i][j][r]);
            }
        }
    }
}

// ----------------- feature-sliced gather aggregation (layers 1-7) ----------
// 8 slices x 32 channels; slice = bid&7 -> XCD-pinned under round-robin
// dispatch. Each XCD's 4MB L2 holds its 3.2MB X-slice; the 6.4MB edge stream
// and Y writes use NON-TEMPORAL ops so they cannot evict the slice (R7's
// failure mode). 16 lanes x uint (2ch) per node, 4 nodes/wave, 16 nodes/blk.
// mode: 0 = fp32 out (layer 7), 2 = bf16 out + fused BN stats.
__global__ void agg_sliced_kernel(const ushort* __restrict__ Xb,
                                  ushort* __restrict__ Yb,
                                  float* __restrict__ Yf,
                                  const int* __restrict__ rowptr,
                                  const int2* __restrict__ edges2,
                                  const float* __restrict__ dinv,
                                  const float* __restrict__ bias,
                                  float* __restrict__ partials,
                                  int mode) {
    __shared__ float sS[4][32];
    __shared__ float sQ[4][32];
    int bid = blockIdx.x;
    int s = bid & 7;               // slice index == target XCD
    int grp = bid >> 3;            // node group of 16
    int tid = threadIdx.x;
    int lane = tid & 63;
    int wid = tid >> 6;
    int q = lane >> 4;             // node-within-wave (quarter)
    int il = lane & 15;            // lane within quarter
    int node = grp * 16 + wid * 4 + q;
    int sil = s * 16 + il;         // uint index within 128-uint row
    const uint* Xu = (const uint*)Xb;

    float di = dinv[node];
    float w0 = di * di;
    uint v = Xu[(size_t)node * 128 + sil];     // own row: temporal (slice-resident)
    float2 bb = ((const float2*)bias)[sil];
    float ax = fmaf(w0, bf_lo(v), bb.x);
    float ay = fmaf(w0, bf_hi(v), bb.y);

    int j = rowptr[node], jend = rowptr[node + 1];
    const long long* E = (const long long*)edges2;
    for (; j + 3 < jend; j += 4) {
        long long e0 = __builtin_nontemporal_load(&E[j + 0]);
        long long e1 = __builtin_nontemporal_load(&E[j + 1]);
        long long e2 = __builtin_nontemporal_load(&E[j + 2]);
        long long e3 = __builtin_nontemporal_load(&E[j + 3]);
        uint u0 = Xu[(size_t)(int)e0 * 128 + sil];
        uint u1 = Xu[(size_t)(int)e1 * 128 + sil];
        uint u2 = Xu[(size_t)(int)e2 * 128 + sil];
        uint u3 = Xu[(size_t)(int)e3 * 128 + sil];
        float t0 = __int_as_float((int)(e0 >> 32));
        float t1 = __int_as_float((int)(e1 >> 32));
        float t2 = __int_as_float((int)(e2 >> 32));
        float t3 = __int_as_float((int)(e3 >> 32));
        ax = fmaf(t0, bf_lo(u0), ax); ay = fmaf(t0, bf_hi(u0), ay);
        ax = fmaf(t1, bf_lo(u1), ax); ay = fmaf(t1, bf_hi(u1), ay);
        ax = fmaf(t2, bf_lo(u2), ax); ay = fmaf(t2, bf_hi(u2), ay);
        ax = fmaf(t3, bf_lo(u3), ax); ay = fmaf(t3, bf_hi(u3), ay);
    }
    for (; j < jend; ++j) {
        long long e = __builtin_nontemporal_load(&E[j]);
        uint u = Xu[(size_t)(int)e * 128 + sil];
        float t = __int_as_float((int)(e >> 32));
        ax = fmaf(t, bf_lo(u), ax);
        ay = fmaf(t, bf_hi(u), ay);
    }

    if (mode != 0) {
        uint w = (uint)f2bf(ax) | ((uint)f2bf(ay) << 16);
        __builtin_nontemporal_store(w, &((uint*)Yb)[(size_t)node * 128 + sil]);
    } else {
        unsigned long long ww = (unsigned long long)__float_as_uint(ax)
                              | ((unsigned long long)__float_as_uint(ay) << 32);
        __builtin_nontemporal_store(
            ww, (unsigned long long*)&((float2*)Yf)[(size_t)node * 128 + sil]);
    }

    if (mode == 2) {
        // fused BN stats for this slice's 32 channels.
        float qx = ax * ax, qy = ay * ay;
        // sum across the 4 node-quarters (lane bits 4,5; il invariant)
        ax += __shfl_xor(ax, 16, 64); ax += __shfl_xor(ax, 32, 64);
        ay += __shfl_xor(ay, 16, 64); ay += __shfl_xor(ay, 32, 64);
        qx += __shfl_xor(qx, 16, 64); qx += __shfl_xor(qx, 32, 64);
        qy += __shfl_xor(qy, 16, 64); qy += __shfl_xor(qy, 32, 64);
        if (q == 0) {
            sS[wid][il * 2 + 0] = ax; sS[wid][il * 2 + 1] = ay;
            sQ[wid][il * 2 + 0] = qx; sQ[wid][il * 2 + 1] = qy;
        }
        __syncthreads();
        if (tid < 32) {
            float ssum = sS[0][tid] + sS[1][tid] + sS[2][tid] + sS[3][tid];
            float qsum = sQ[0][tid] + sQ[1][tid] + sQ[2][tid] + sQ[3][tid];
            int c = s * 32 + tid;
            float* P = partials + (size_t)(grp & 255) * 512;
            atomicAdd(&P[c], ssum);
            atomicAdd(&P[256 + c], qsum);
        }
    }
}

// ------------------------------- BatchNorm ---------------------------------
// Stage A over bf16 Yb (layer 0 only now): 256 blocks, overwrite partials.
#define BN_RPB 196
__global__ void bn_stats_kernel(const ushort* __restrict__ Yb, float* __restrict__ partials) {
    __shared__ float4 redS[4][64];
    __shared__ float4 redQ[4][64];
    int c = threadIdx.x & 63, g = threadIdx.x >> 6;
    int r0 = blockIdx.x * BN_RPB;
    int rend = min(r0 + BN_RPB, NN);
    const uint2* Y2 = (const uint2*)Yb;
    float4 s = make_float4(0.f, 0.f, 0.f, 0.f);
    float4 q = make_float4(0.f, 0.f, 0.f, 0.f);
    int r = r0 + g;
    for (; r + 28 < rend; r += 32) {
        uint2 u0 = Y2[(size_t)(r +  0) * 64 + c];
        uint2 u1 = Y2[(size_t)(r +  4) * 64 + c];
        uint2 u2 = Y2[(size_t)(r +  8) * 64 + c];
        uint2 u3 = Y2[(size_t)(r + 12) * 64 + c];
        uint2 u4 = Y2[(size_t)(r + 16) * 64 + c];
        uint2 u5 = Y2[(size_t)(r + 20) * 64 + c];
        uint2 u6 = Y2[(size_t)(r + 24) * 64 + c];
        uint2 u7 = Y2[(size_t)(r + 28) * 64 + c];
        #pragma unroll
        for (int t = 0; t < 8; ++t) {
            uint2 u = (t == 0) ? u0 : (t == 1) ? u1 : (t == 2) ? u2 : (t == 3) ? u3
                    : (t == 4) ? u4 : (t == 5) ? u5 : (t == 6) ? u6 : u7;
            float vx = bf_lo(u.x), vy = bf_hi(u.x), vz = bf_lo(u.y), vw = bf_hi(u.y);
            s.x += vx; s.y += vy; s.z += vz; s.w += vw;
            q.x = fmaf(vx, vx, q.x); q.y = fmaf(vy, vy, q.y);
            q.z = fmaf(vz, vz, q.z); q.w = fmaf(vw, vw, q.w);
        }
    }
    for (; r < rend; r += 4) {
        uint2 u = Y2[(size_t)r * 64 + c];
        float vx = bf_lo(u.x), vy = bf_hi(u.x), vz = bf_lo(u.y), vw = bf_hi(u.y);
        s.x += vx; s.y += vy; s.z += vz; s.w += vw;
        q.x = fmaf(vx, vx, q.x); q.y = fmaf(vy, vy, q.y);
        q.z = fmaf(vz, vz, q.z); q.w = fmaf(vw, vw, q.w);
    }
    redS[g][c] = s; redQ[g][c] = q;
    __syncthreads();
    if (g == 0) {
        float4 s1 = redS[1][c], s2 = redS[2][c], s3 = redS[3][c];
        float4 q1 = redQ[1][c], q2 = redQ[2][c], q3 = redQ[3][c];
        s.x += s1.x + s2.x + s3.x; s.y += s1.y + s2.y + s3.y;
        s.z += s1.z + s2.z + s3.z; s.w += s1.w + s2.w + s3.w;
        q.x += q1.x + q2.x + q3.x; q.y += q1.y + q2.y + q3.y;
        q.z += q1.z + q2.z + q3.z; q.w += q1.w + q2.w + q3.w;
        float* P = partials + (size_t)blockIdx.x * 512;
        *(float4*)&P[c * 4] = s;
        *(float4*)&P[256 + c * 4] = q;
    }
}

// Stage B + finalize: reduce 256 partial rows, emit scale/shift, then zero
// the consumed columns so the next layer's fused-agg accumulation starts clean.
__global__ void bn_finalize_kernel(const float* __restrict__ partials_in,
                                   float* __restrict__ partials,
                                   const float* __restrict__ g,
                                   const float* __restrict__ be,
                                   float* __restrict__ scsh) {
    __shared__ float rs[8][32], rq[8][32];
    int cl = threadIdx.x & 31, gr = threadIdx.x >> 5;
    int col = blockIdx.x * 32 + cl;
    float s = 0.f, q = 0.f;
    #pragma unroll 4
    for (int r = gr; r < 256; r += 8) {
        s += partials_in[(size_t)r * 512 + col];
        q += partials_in[(size_t)r * 512 + 256 + col];
    }
    rs[gr][cl] = s; rq[gr][cl] = q;
    __syncthreads();
    if (gr == 0) {
        #pragma unroll
        for (int i = 1; i < 8; ++i) { s += rs[i][cl]; q += rq[i][cl]; }
        const float invN = 1.0f / (float)NN;
        float m = s * invN;
        float var = fmaf(-m, m, q * invN);
        float sc = rsqrtf(var + 1e-5f) * g[col];
        scsh[col] = sc;
        scsh[256 + col] = fmaf(-m, sc, be[col]);
    }
    // zero this block's columns for next accumulation (all reads done above)
    for (int r = gr; r < 256; r += 8) {
        partials[(size_t)r * 512 + col] = 0.f;
        partials[(size_t)r * 512 + 256 + col] = 0.f;
    }
}

// ---------------------------------------------------------------------------

extern "C" void kernel_launch(void* const* d_in, const int* in_sizes, int n_in,
                              void* d_out, int out_size, void* d_ws, size_t ws_size,
                              hipStream_t stream) {
    const float* h   = (const float*)d_in[0];
    const int*   ei  = (const int*)d_in[1];
    const float* ew  = (const float*)d_in[2];
    const float* W1  = (const float*)d_in[3];
    const float* b1  = (const float*)d_in[4];
    const float* g1  = (const float*)d_in[5];
    const float* be1 = (const float*)d_in[6];
    const float* Wm  = (const float*)d_in[7];
    const float* bm  = (const float*)d_in[8];
    const float* gm  = (const float*)d_in[9];
    const float* bem = (const float*)d_in[10];
    const float* Wl  = (const float*)d_in[11];
    const float* bl  = (const float*)d_in[12];

    const int* src = ei;
    const int* dst = ei + NE;

    char* ws = (char*)d_ws;
    size_t off = 0;
    auto alloc = [&](size_t bytes) { size_t o = off; off = (off + bytes + 255) & ~(size_t)255; return o; };
    ushort* Xb      = (ushort*)(ws + alloc((size_t)NN * DD * 2));
    ushort* Yb      = (ushort*)(ws + alloc((size_t)NN * DD * 2));
    ushort* Bt      = (ushort*)(ws + alloc((size_t)7 * DD * DD * 2));
    unsigned long long* cells = (unsigned long long*)(ws + alloc((size_t)NN * 8));
    float*  dinv    = (float*) (ws + alloc((size_t)NN * 4));
    float*  partials= (float*) (ws + alloc((size_t)256 * 512 * 4));
    float*  scsh    = (float*) (ws + alloc(512 * 4));
    int*    rowptr  = (int*)   (ws + alloc((size_t)(NN + 1) * 4));
    int*    cnt     = (int*)   (ws + alloc((size_t)NN * 4));
    int*    rank    = (int*)   (ws + alloc((size_t)NE * 4));
    int2*   edges2  = (int2*)  (ws + alloc((size_t)NE * 8));
    (void)ws_size;

    // Hagg (N x 6 fp32 = 1.2 MB) aliases rank (3.2 MB): rank is dead after
    // fill_kernel, agg6 runs strictly after fill on the same stream.
    float* Hagg = (float*)rank;

    float* OUT = (float*)d_out;

    const int gN = (NN + 255) / 256;
    const int gE = (NE + 255) / 256;

    // --- gcn_norm + CSR build ---
    hipMemsetAsync(cells, 0, (size_t)NN * 8, stream);
    edge_stat_kernel<<<gE, 256, 0, stream>>>(dst, ew, cells, rank);
    deg_finish_kernel<<<gN, 256, 0, stream>>>(cells, cnt, dinv);
    scan_kernel<<<1, 1024, 0, stream>>>(cnt, rowptr, NN);
    fill_kernel<<<gE, 256, 0, stream>>>(src, dst, ew, dinv, rank, rowptr, edges2);

    // --- weights -> bf16 transposed ---
    wcvt_kernel<<<(7 * 65536 + 255) / 256, 256, 0, stream>>>(Wm, Wl, Bt);

    // --- layer 0: agg in 6-dim space, then 6->256 GEMM (+bias), BN stats ---
    agg6_kernel<<<gN, 256, 0, stream>>>(h, rowptr, edges2, dinv, Hagg);
    gemm0_kernel<<<NN / 8, 256, 0, stream>>>(Hagg, W1, b1, Yb);
    bn_stats_kernel<<<256, 256, 0, stream>>>(Yb, partials);
    bn_finalize_kernel<<<8, 256, 0, stream>>>(partials, partials, g1, be1, scsh);

    // --- layers 1..7 ---
    for (int l = 1; l < 8; ++l) {
        const ushort* Btl = Bt + (size_t)(l - 1) * DD * DD;
        gemm_bn_kernel<<<(NN + 63) / 64, 256, 0, stream>>>(Yb, Btl, scsh, Xb, NN);
        const float* b_l = (l <= 6) ? bm + (l - 1) * 256 : bl;
        int mode = (l < 7) ? 2 : 0;
        agg_sliced_kernel<<<(NN / 16) * 8, 256, 0, stream>>>(
            Xb, Yb, OUT, rowptr, edges2, dinv, b_l, partials, mode);
        if (l < 7) {
            bn_finalize_kernel<<<8, 256, 0, stream>>>(
                partials, partials, gm + (l - 1) * 256, bem + (l - 1) * 256, scsh);
        }
    }
}

// Round 7
// 854.856 us; speedup vs baseline: 1.8718x; 1.8718x over previous
//
#include <hip/hip_runtime.h>
#include <hip/hip_bf16.h>

// ---------------------------------------------------------------------------
// EncoderGAE: 8-layer GCN encoder on MI355X.
// R13: full revert to R9 structure (best measured: 929.6us), plus:
//  (a) gemm_bn: reg-staged double-buffered LDS pipeline, ONE barrier/K-step
//      (issue next-step global loads early; compute from buf[s&1]; write
//      buf[(s+1)&1] after MFMAs). Hides the ~600-900cy global latency that
//      R9 exposed serially each step.
//  (b) single-block scan -> 3-tier hierarchical scan (sum/offsets/local).
//  (c) bn_stats dispatch removed: layer-0 BN stats fused into gemm0
//      (partials memset once at start; bn_finalize re-zeroes after use).
//  Slicing/NT experiments (R7/R12) permanently abandoned: two falsifications
//  of XCD slice-residency; agg is compulsory-volume bound at ~2.9 TB/s.
// ---------------------------------------------------------------------------

#define NN 50000
#define NE 800000
#define DD 256
#define NBLK 196   // ceil((NN+1)/256)

typedef __attribute__((ext_vector_type(8))) short short8;
typedef __attribute__((ext_vector_type(4))) float f32x4;

static __device__ __forceinline__ ushort f2bf(float f) {
    unsigned u = __float_as_uint(f);
    unsigned r = (u + 0x7fffu + ((u >> 16) & 1u)) >> 16;   // RNE
    return (ushort)r;
}
static __device__ __forceinline__ float bf_lo(unsigned x) {
    return __uint_as_float(x << 16);
}
static __device__ __forceinline__ float bf_hi(unsigned x) {
    return __uint_as_float(x & 0xffff0000u);
}

// ------------------------- gcn_norm + CSR build ----------------------------
__global__ void edge_stat_kernel(const int* __restrict__ dst,
                                 const float* __restrict__ ew,
                                 unsigned long long* __restrict__ cells,
                                 int* __restrict__ rank) {
    int e = blockIdx.x * 256 + threadIdx.x;
    if (e < NE) {
        unsigned long long inc =
            (1ULL << 40) | (unsigned long long)(unsigned)rintf(ew[e] * 16777216.0f);
        unsigned long long old = atomicAdd(&cells[dst[e]], inc);
        rank[e] = (int)(old >> 40);
    }
}

__global__ void deg_finish_kernel(const unsigned long long* __restrict__ cells,
                                  int* __restrict__ cnt,
                                  float* __restrict__ dinv) {
    int i = blockIdx.x * 256 + threadIdx.x;
    if (i < NN) {
        unsigned long long c = cells[i];
        cnt[i] = (int)(c >> 40);
        float deg = 1.0f + (float)(c & ((1ULL << 40) - 1)) * (1.0f / 16777216.0f);
        dinv[i] = rsqrtf(deg);  // deg >= 1 always (self-loop)
    }
}

// --- 3-tier scan: per-block sums -> 1-block offset scan -> local scan ------
__global__ void scan_sum_kernel(const int* __restrict__ cnt, int* __restrict__ bsum) {
    int tid = threadIdx.x;
    int i = blockIdx.x * 256 + tid;
    int v = (i < NN) ? cnt[i] : 0;
    #pragma unroll
    for (int o = 1; o < 64; o <<= 1) v += __shfl_xor(v, o, 64);
    __shared__ int ws[4];
    if ((tid & 63) == 0) ws[tid >> 6] = v;
    __syncthreads();
    if (tid == 0) bsum[blockIdx.x] = ws[0] + ws[1] + ws[2] + ws[3];
}

__global__ void scan_off_kernel(const int* __restrict__ bsum, int* __restrict__ boff) {
    int tid = threadIdx.x;
    int lane = tid & 63, wid = tid >> 6;
    int v = (tid < NBLK) ? bsum[tid] : 0;
    int x = v;
    #pragma unroll
    for (int o = 1; o < 64; o <<= 1) {
        int y = __shfl_up(x, o, 64);
        if (lane >= o) x += y;
    }
    __shared__ int ws[4];
    if (lane == 63) ws[wid] = x;
    __syncthreads();
    int add = 0;
    #pragma unroll
    for (int w = 0; w < 4; ++w) if (w < wid) add += ws[w];
    boff[tid] = x + add - v;   // exclusive block offset
}

__global__ void scan_local_kernel(const int* __restrict__ cnt,
                                  const int* __restrict__ boff,
                                  int* __restrict__ rowptr) {
    int tid = threadIdx.x;
    int lane = tid & 63, wid = tid >> 6;
    int i = blockIdx.x * 256 + tid;
    int v = (i < NN) ? cnt[i] : 0;
    int x = v;
    #pragma unroll
    for (int o = 1; o < 64; o <<= 1) {
        int y = __shfl_up(x, o, 64);
        if (lane >= o) x += y;
    }
    __shared__ int ws[4];
    if (lane == 63) ws[wid] = x;
    __syncthreads();
    int add = boff[blockIdx.x];
    #pragma unroll
    for (int w = 0; w < 4; ++w) if (w < wid) add += ws[w];
    if (i <= NN) rowptr[i] = x + add - v;   // exclusive
}

// Atomic-free fill: position = rowptr[dst] + rank; one 8B write per edge.
__global__ void fill_kernel(const int* __restrict__ src,
                            const int* __restrict__ dst,
                            const float* __restrict__ ew,
                            const float* __restrict__ dinv,
                            const int* __restrict__ rank,
                            const int* __restrict__ rowptr,
                            int2* __restrict__ edges2) {
    int e = blockIdx.x * 256 + threadIdx.x;
    if (e < NE) {
        int s = src[e], d = dst[e];
        float nrm = dinv[s] * ew[e] * dinv[d];
        int p = rowptr[d] + rank[e];
        edges2[p] = make_int2(s, __float_as_int(nrm));
    }
}

// ---------------------- weight transpose + bf16 cvt ------------------------
__global__ void wcvt_kernel(const float* __restrict__ Wm,
                            const float* __restrict__ Wl,
                            ushort* __restrict__ Bt) {
    int idx = blockIdx.x * 256 + threadIdx.x;
    if (idx >= 7 * 65536) return;
    int l = idx >> 16;
    int nk = idx & 65535;
    int n = nk >> 8, k = nk & 255;
    const float* W = (l < 6) ? (Wm + (size_t)l * 65536) : Wl;
    Bt[idx] = f2bf(W[k * 256 + n]);
}

// ------------------- layer-0: aggregate raw h (N x 6) ----------------------
// agg(h @ W1) == agg(h) @ W1 by row-linearity; h is 1.2 MB -> L2-resident.
__global__ void agg6_kernel(const float* __restrict__ h,
                            const int* __restrict__ rowptr,
                            const int2* __restrict__ edges2,
                            const float* __restrict__ dinv,
                            float* __restrict__ Hagg) {
    int node = blockIdx.x * 256 + threadIdx.x;
    if (node >= NN) return;
    float di = dinv[node];
    float w0 = di * di;
    const float2* hp = (const float2*)(h + (size_t)node * 6);
    float2 v0 = hp[0], v1 = hp[1], v2 = hp[2];
    float a0 = w0 * v0.x, a1 = w0 * v0.y, a2 = w0 * v1.x;
    float a3 = w0 * v1.y, a4 = w0 * v2.x, a5 = w0 * v2.y;
    int j = rowptr[node], jend = rowptr[node + 1];
    for (; j + 1 < jend; j += 2) {
        int2 e0 = edges2[j], e1 = edges2[j + 1];
        const float2* p0 = (const float2*)(h + (size_t)e0.x * 6);
        const float2* p1 = (const float2*)(h + (size_t)e1.x * 6);
        float2 x0 = p0[0], x1 = p0[1], x2 = p0[2];
        float2 y0 = p1[0], y1 = p1[1], y2 = p1[2];
        float t0 = __int_as_float(e0.y);
        float t1 = __int_as_float(e1.y);
        a0 = fmaf(t0, x0.x, a0); a1 = fmaf(t0, x0.y, a1);
        a2 = fmaf(t0, x1.x, a2); a3 = fmaf(t0, x1.y, a3);
        a4 = fmaf(t0, x2.x, a4); a5 = fmaf(t0, x2.y, a5);
        a0 = fmaf(t1, y0.x, a0); a1 = fmaf(t1, y0.y, a1);
        a2 = fmaf(t1, y1.x, a2); a3 = fmaf(t1, y1.y, a3);
        a4 = fmaf(t1, y2.x, a4); a5 = fmaf(t1, y2.y, a5);
    }
    if (j < jend) {
        int2 e = edges2[j];
        const float2* p = (const float2*)(h + (size_t)e.x * 6);
        float2 x0 = p[0], x1 = p[1], x2 = p[2];
        float t = __int_as_float(e.y);
        a0 = fmaf(t, x0.x, a0); a1 = fmaf(t, x0.y, a1);
        a2 = fmaf(t, x1.x, a2); a3 = fmaf(t, x1.y, a3);
        a4 = fmaf(t, x2.x, a4); a5 = fmaf(t, x2.y, a5);
    }
    float2* op = (float2*)(Hagg + (size_t)node * 6);
    op[0] = make_float2(a0, a1);
    op[1] = make_float2(a2, a3);
    op[2] = make_float2(a4, a5);
}

// Layer-0 GEMM with fused BN stats: Yb = bf16(Hagg @ W1 + b1); per-column
// sum/sumsq accumulated over the block's 8 rows -> 2 atomics into partials.
__global__ void gemm0_kernel(const float* __restrict__ Hagg,
                             const float* __restrict__ W1,
                             const float* __restrict__ b1,
                             ushort* __restrict__ Yb,
                             float* __restrict__ partials) {
    int f = threadIdx.x;
    float w0 = W1[f],        w1 = W1[256 + f],  w2 = W1[512 + f];
    float w3 = W1[768 + f],  w4 = W1[1024 + f], w5 = W1[1280 + f];
    float bb = b1[f];
    int n0 = blockIdx.x * 8;
    float ssum = 0.f, qsum = 0.f;
    #pragma unroll
    for (int t = 0; t < 8; ++t) {
        int i = n0 + t;
        const float2* hp = (const float2*)(Hagg + (size_t)i * 6);
        float2 h0 = hp[0], h1 = hp[1], h2 = hp[2];
        float s = bb;
        s = fmaf(h0.x, w0, s); s = fmaf(h0.y, w1, s);
        s = fmaf(h1.x, w2, s); s = fmaf(h1.y, w3, s);
        s = fmaf(h2.x, w4, s); s = fmaf(h2.y, w5, s);
        Yb[(size_t)i * 256 + f] = f2bf(s);
        ssum += s;
        qsum = fmaf(s, s, qsum);
    }
    float* P = partials + (size_t)(blockIdx.x & 255) * 512;
    atomicAdd(&P[f], ssum);
    atomicAdd(&P[256 + f], qsum);
}

// ---------------- MFMA bf16 GEMM with fused BN+leakyReLU on A --------------
// C[M,256] = leaky(BN(Yb)) @ Bt^T. Tile 64x256, BK=32, 4 waves (col-split).
// Reg-staged double-buffered LDS pipeline, ONE barrier per K-step:
//   iter s: [barrier] -> issue loads(s+1) -> ds_read buf[s&1] + 16 MFMA
//           -> transform + write buf[(s+1)&1]
// The start-of-iter barrier both publishes buf[s&1] writes and separates
// iter s-1's reads of buf[(s+1)&1] from this iter's writes to it.
__launch_bounds__(256)
__global__ void gemm_bn_kernel(const ushort* __restrict__ Yb,
                               const ushort* __restrict__ Bt,
                               const float* __restrict__ scsh,
                               ushort* __restrict__ C, int M) {
    __shared__ __align__(16) ushort As[2][64][40];
    __shared__ __align__(16) ushort Bs[2][256][40];
    __shared__ float sc_s[256], sh_s[256];
    int tid = threadIdx.x;
    sc_s[tid] = scsh[tid];
    sh_s[tid] = scsh[256 + tid];
    int lane = tid & 63, wc = tid >> 6;      // wave = col quarter
    int lm = lane & 15, kq = lane >> 4;
    int row0 = blockIdx.x * 64;
    int arow = tid >> 2;                     // 0..63  (A staging row)
    int ah = (tid & 3) * 8;                  // A k-offset 0/8/16/24
    int bsub = tid >> 2;                     // 0..63  (B staging row in group)
    int bh = (tid & 3) * 8;                  // B k-offset

    int agrow = row0 + arow;
    if (agrow >= M) agrow = M - 1;           // clamp; padding rows never stored
    const ushort* Agp = Yb + (size_t)agrow * 256 + ah;

    f32x4 acc[4][4] = {};

    // ---- prologue: stage k0=0 into buf 0 ----
    {
        uint4 p = *(const uint4*)Agp;
        uint in[4] = {p.x, p.y, p.z, p.w};
        uint packed[4];
        #pragma unroll
        for (int t = 0; t < 4; ++t) {
            int cb = ah + t * 2;
            float o0 = fmaf(bf_lo(in[t]), scsh[cb + 0], scsh[256 + cb + 0]);
            float o1 = fmaf(bf_hi(in[t]), scsh[cb + 1], scsh[256 + cb + 1]);
            o0 = fmaxf(o0, 0.01f * o0);
            o1 = fmaxf(o1, 0.01f * o1);
            packed[t] = (uint)f2bf(o0) | ((uint)f2bf(o1) << 16);
        }
        *(uint4*)&As[0][arow][ah] = make_uint4(packed[0], packed[1], packed[2], packed[3]);
        #pragma unroll
        for (int rr = 0; rr < 4; ++rr) {
            int brow = rr * 64 + bsub;
            *(uint4*)&Bs[0][brow][bh] = *(const uint4*)(Bt + (size_t)brow * 256 + bh);
        }
    }

    #pragma unroll
    for (int s = 0; s < 8; ++s) {
        int k0 = s * 32;
        __syncthreads();   // publishes buf[s&1]; fences last iter's reads
        // issue next-step global loads (latency hides under ds_read + MFMA)
        uint4 na = make_uint4(0, 0, 0, 0);
        uint4 nb0, nb1, nb2, nb3;
        if (s < 7) {
            na  = *(const uint4*)(Agp + k0 + 32);
            nb0 = *(const uint4*)(Bt + (size_t)(0 * 64 + bsub) * 256 + k0 + 32 + bh);
            nb1 = *(const uint4*)(Bt + (size_t)(1 * 64 + bsub) * 256 + k0 + 32 + bh);
            nb2 = *(const uint4*)(Bt + (size_t)(2 * 64 + bsub) * 256 + k0 + 32 + bh);
            nb3 = *(const uint4*)(Bt + (size_t)(3 * 64 + bsub) * 256 + k0 + 32 + bh);
        }
        // compute from buf[s&1]
        int cur = s & 1;
        short8 af[4], bfj[4];
        #pragma unroll
        for (int i = 0; i < 4; ++i)
            af[i] = *(const short8*)&As[cur][i * 16 + lm][kq * 8];
        #pragma unroll
        for (int j = 0; j < 4; ++j)
            bfj[j] = *(const short8*)&Bs[cur][wc * 64 + j * 16 + lm][kq * 8];
        #pragma unroll
        for (int i = 0; i < 4; ++i)
            #pragma unroll
            for (int j = 0; j < 4; ++j)
                acc[i][j] = __builtin_amdgcn_mfma_f32_16x16x32_bf16(
                    af[i], bfj[j], acc[i][j], 0, 0, 0);
        // transform + write next tile into buf[cur^1]
        if (s < 7) {
            int nxt = cur ^ 1;
            uint in[4] = {na.x, na.y, na.z, na.w};
            uint packed[4];
            #pragma unroll
            for (int t = 0; t < 4; ++t) {
                int cb = k0 + 32 + ah + t * 2;
                float o0 = fmaf(bf_lo(in[t]), sc_s[cb + 0], sh_s[cb + 0]);
                float o1 = fmaf(bf_hi(in[t]), sc_s[cb + 1], sh_s[cb + 1]);
                o0 = fmaxf(o0, 0.01f * o0);
                o1 = fmaxf(o1, 0.01f * o1);
                packed[t] = (uint)f2bf(o0) | ((uint)f2bf(o1) << 16);
            }
            *(uint4*)&As[nxt][arow][ah] = make_uint4(packed[0], packed[1], packed[2], packed[3]);
            *(uint4*)&Bs[nxt][0 * 64 + bsub][bh] = nb0;
            *(uint4*)&Bs[nxt][1 * 64 + bsub][bh] = nb1;
            *(uint4*)&Bs[nxt][2 * 64 + bsub][bh] = nb2;
            *(uint4*)&Bs[nxt][3 * 64 + bsub][bh] = nb3;
        }
    }

    // Epilogue: C/D layout col=lane&15, row=(lane>>4)*4+reg
    #pragma unroll
    for (int i = 0; i < 4; ++i) {
        #pragma unroll
        for (int j = 0; j < 4; ++j) {
            int col = wc * 64 + j * 16 + lm;
            #pragma unroll
            for (int r = 0; r < 4; ++r) {
                int grow = row0 + i * 16 + kq * 4 + r;
                if (grow < M) C[(size_t)grow * 256 + col] = f2bf(acc[i][j][r]);
            }
        }
    }
}

// ---------------------- gather aggregation (bf16 X) ------------------------
// One wave per dst node; 8x unrolled edge loop. mode: 0 = fp32 out (layer 7),
// 2 = bf16 out + fused BN-stat accumulation into partials.
__global__ void agg_kernel(const ushort* __restrict__ Xb,
                           ushort* __restrict__ Yb,
                           float* __restrict__ Yf,
                           const int* __restrict__ rowptr,
                           const int2* __restrict__ edges2,
                           const float* __restrict__ dinv,
                           const float* __restrict__ bias,
                           float* __restrict__ partials,
                           int mode) {
    __shared__ float sS[1024];
    __shared__ float sQ[1024];
    int tid = threadIdx.x;
    int wid = tid >> 6;
    int lane = tid & 63;
    int node = (blockIdx.x << 2) + wid;   // grid exact: 12500 blocks * 4 = NN
    const uint2* X2 = (const uint2*)Xb;
    float di = dinv[node];
    float w0 = di * di;
    uint2 v = X2[(size_t)node * 64 + lane];
    float4 bb = ((const float4*)bias)[lane];
    float ax = fmaf(w0, bf_lo(v.x), bb.x);
    float ay = fmaf(w0, bf_hi(v.x), bb.y);
    float az = fmaf(w0, bf_lo(v.y), bb.z);
    float aw = fmaf(w0, bf_hi(v.y), bb.w);
    int j = rowptr[node], jend = rowptr[node + 1];
    int jstop = j + ((jend - j) & ~7);
    for (; j < jstop; j += 8) {
        int2 e0 = edges2[j + 0], e1 = edges2[j + 1], e2 = edges2[j + 2], e3 = edges2[j + 3];
        int2 e4 = edges2[j + 4], e5 = edges2[j + 5], e6 = edges2[j + 6], e7 = edges2[j + 7];
        uint2 u0 = X2[(size_t)e0.x * 64 + lane];
        uint2 u1 = X2[(size_t)e1.x * 64 + lane];
        uint2 u2 = X2[(size_t)e2.x * 64 + lane];
        uint2 u3 = X2[(size_t)e3.x * 64 + lane];
        uint2 u4 = X2[(size_t)e4.x * 64 + lane];
        uint2 u5 = X2[(size_t)e5.x * 64 + lane];
        uint2 u6 = X2[(size_t)e6.x * 64 + lane];
        uint2 u7 = X2[(size_t)e7.x * 64 + lane];
        float t0 = __int_as_float(e0.y), t1 = __int_as_float(e1.y);
        float t2 = __int_as_float(e2.y), t3 = __int_as_float(e3.y);
        float t4 = __int_as_float(e4.y), t5 = __int_as_float(e5.y);
        float t6 = __int_as_float(e6.y), t7 = __int_as_float(e7.y);
        ax = fmaf(t0, bf_lo(u0.x), ax); ay = fmaf(t0, bf_hi(u0.x), ay);
        az = fmaf(t0, bf_lo(u0.y), az); aw = fmaf(t0, bf_hi(u0.y), aw);
        ax = fmaf(t1, bf_lo(u1.x), ax); ay = fmaf(t1, bf_hi(u1.x), ay);
        az = fmaf(t1, bf_lo(u1.y), az); aw = fmaf(t1, bf_hi(u1.y), aw);
        ax = fmaf(t2, bf_lo(u2.x), ax); ay = fmaf(t2, bf_hi(u2.x), ay);
        az = fmaf(t2, bf_lo(u2.y), az); aw = fmaf(t2, bf_hi(u2.y), aw);
        ax = fmaf(t3, bf_lo(u3.x), ax); ay = fmaf(t3, bf_hi(u3.x), ay);
        az = fmaf(t3, bf_lo(u3.y), az); aw = fmaf(t3, bf_hi(u3.y), aw);
        ax = fmaf(t4, bf_lo(u4.x), ax); ay = fmaf(t4, bf_hi(u4.x), ay);
        az = fmaf(t4, bf_lo(u4.y), az); aw = fmaf(t4, bf_hi(u4.y), aw);
        ax = fmaf(t5, bf_lo(u5.x), ax); ay = fmaf(t5, bf_hi(u5.x), ay);
        az = fmaf(t5, bf_lo(u5.y), az); aw = fmaf(t5, bf_hi(u5.y), aw);
        ax = fmaf(t6, bf_lo(u6.x), ax); ay = fmaf(t6, bf_hi(u6.x), ay);
        az = fmaf(t6, bf_lo(u6.y), az); aw = fmaf(t6, bf_hi(u6.y), aw);
        ax = fmaf(t7, bf_lo(u7.x), ax); ay = fmaf(t7, bf_hi(u7.x), ay);
        az = fmaf(t7, bf_lo(u7.y), az); aw = fmaf(t7, bf_hi(u7.y), aw);
    }
    for (; j < jend; ++j) {
        int2 e = edges2[j];
        float wt = __int_as_float(e.y);
        uint2 u = X2[(size_t)e.x * 64 + lane];
        ax = fmaf(wt, bf_lo(u.x), ax);
        ay = fmaf(wt, bf_hi(u.x), ay);
        az = fmaf(wt, bf_lo(u.y), az);
        aw = fmaf(wt, bf_hi(u.y), aw);
    }
    if (mode != 0) {
        uint lo = (uint)f2bf(ax) | ((uint)f2bf(ay) << 16);
        uint hi = (uint)f2bf(az) | ((uint)f2bf(aw) << 16);
        ((uint2*)Yb)[(size_t)node * 64 + lane] = make_uint2(lo, hi);
    } else {
        ((float4*)Yf)[(size_t)node * 64 + lane] = make_float4(ax, ay, az, aw);
    }
    if (mode == 2) {
        // fused BN stats: block reduce over 4 rows, atomic into 256-bin partials
        *(float4*)&sS[wid * 256 + (lane << 2)] = make_float4(ax, ay, az, aw);
        *(float4*)&sQ[wid * 256 + (lane << 2)] =
            make_float4(ax * ax, ay * ay, az * az, aw * aw);
        __syncthreads();
        int f = tid;
        float s = sS[f] + sS[256 + f] + sS[512 + f] + sS[768 + f];
        float q = sQ[f] + sQ[256 + f] + sQ[512 + f] + sQ[768 + f];
        float* P = partials + (size_t)(blockIdx.x & 255) * 512;
        atomicAdd(&P[f], s);
        atomicAdd(&P[256 + f], q);
    }
}

// ------------------------------- BatchNorm ---------------------------------
// finalize: reduce 256 partial rows, emit scale/shift, then zero the consumed
// columns so the next layer's fused accumulation starts clean.
__global__ void bn_finalize_kernel(const float* __restrict__ partials_in,
                                   float* __restrict__ partials,
                                   const float* __restrict__ g,
                                   const float* __restrict__ be,
                                   float* __restrict__ scsh) {
    __shared__ float rs[8][32], rq[8][32];
    int cl = threadIdx.x & 31, gr = threadIdx.x >> 5;
    int col = blockIdx.x * 32 + cl;
    float s = 0.f, q = 0.f;
    #pragma unroll 4
    for (int r = gr; r < 256; r += 8) {
        s += partials_in[(size_t)r * 512 + col];
        q += partials_in[(size_t)r * 512 + 256 + col];
    }
    rs[gr][cl] = s; rq[gr][cl] = q;
    __syncthreads();
    if (gr == 0) {
        #pragma unroll
        for (int i = 1; i < 8; ++i) { s += rs[i][cl]; q += rq[i][cl]; }
        const float invN = 1.0f / (float)NN;
        float m = s * invN;
        float var = fmaf(-m, m, q * invN);
        float sc = rsqrtf(var + 1e-5f) * g[col];
        scsh[col] = sc;
        scsh[256 + col] = fmaf(-m, sc, be[col]);
    }
    // zero this block's columns for next accumulation (all reads done above)
    for (int r = gr; r < 256; r += 8) {
        partials[(size_t)r * 512 + col] = 0.f;
        partials[(size_t)r * 512 + 256 + col] = 0.f;
    }
}

// ---------------------------------------------------------------------------

extern "C" void kernel_launch(void* const* d_in, const int* in_sizes, int n_in,
                              void* d_out, int out_size, void* d_ws, size_t ws_size,
                              hipStream_t stream) {
    const float* h   = (const float*)d_in[0];
    const int*   ei  = (const int*)d_in[1];
    const float* ew  = (const float*)d_in[2];
    const float* W1  = (const float*)d_in[3];
    const float* b1  = (const float*)d_in[4];
    const float* g1  = (const float*)d_in[5];
    const float* be1 = (const float*)d_in[6];
    const float* Wm  = (const float*)d_in[7];
    const float* bm  = (const float*)d_in[8];
    const float* gm  = (const float*)d_in[9];
    const float* bem = (const float*)d_in[10];
    const float* Wl  = (const float*)d_in[11];
    const float* bl  = (const float*)d_in[12];

    const int* src = ei;
    const int* dst = ei + NE;

    char* ws = (char*)d_ws;
    size_t off = 0;
    auto alloc = [&](size_t bytes) { size_t o = off; off = (off + bytes + 255) & ~(size_t)255; return o; };
    ushort* Xb      = (ushort*)(ws + alloc((size_t)NN * DD * 2));
    ushort* Yb      = (ushort*)(ws + alloc((size_t)NN * DD * 2));
    ushort* Bt      = (ushort*)(ws + alloc((size_t)7 * DD * DD * 2));
    unsigned long long* cells = (unsigned long long*)(ws + alloc((size_t)NN * 8));
    float*  dinv    = (float*) (ws + alloc((size_t)NN * 4));
    float*  partials= (float*) (ws + alloc((size_t)256 * 512 * 4));
    float*  scsh    = (float*) (ws + alloc(512 * 4));
    int*    rowptr  = (int*)   (ws + alloc((size_t)(NN + 1) * 4));
    int*    cnt     = (int*)   (ws + alloc((size_t)NN * 4));
    int*    rank    = (int*)   (ws + alloc((size_t)NE * 4));
    int2*   edges2  = (int2*)  (ws + alloc((size_t)NE * 8));
    (void)ws_size;

    // Aliases into dead regions:
    //   Hagg (N x 6 fp32 = 1.2 MB) <- rank (dead after fill_kernel).
    //   bsum/boff (256 ints each)  <- cells (dead after deg_finish).
    float* Hagg = (float*)rank;
    int* bsum = (int*)cells;
    int* boff = bsum + 256;

    float* OUT = (float*)d_out;

    const int gN = (NN + 255) / 256;
    const int gE = (NE + 255) / 256;

    // --- gcn_norm + CSR build ---
    hipMemsetAsync(cells, 0, (size_t)NN * 8, stream);
    hipMemsetAsync(partials, 0, (size_t)256 * 512 * 4, stream);
    edge_stat_kernel<<<gE, 256, 0, stream>>>(dst, ew, cells, rank);
    deg_finish_kernel<<<gN, 256, 0, stream>>>(cells, cnt, dinv);
    scan_sum_kernel<<<NBLK, 256, 0, stream>>>(cnt, bsum);
    scan_off_kernel<<<1, 256, 0, stream>>>(bsum, boff);
    scan_local_kernel<<<NBLK, 256, 0, stream>>>(cnt, boff, rowptr);
    fill_kernel<<<gE, 256, 0, stream>>>(src, dst, ew, dinv, rank, rowptr, edges2);

    // --- weights -> bf16 transposed ---
    wcvt_kernel<<<(7 * 65536 + 255) / 256, 256, 0, stream>>>(Wm, Wl, Bt);

    // --- layer 0: agg in 6-dim space, 6->256 GEMM (+bias, fused BN stats) ---
    agg6_kernel<<<gN, 256, 0, stream>>>(h, rowptr, edges2, dinv, Hagg);
    gemm0_kernel<<<NN / 8, 256, 0, stream>>>(Hagg, W1, b1, Yb, partials);
    bn_finalize_kernel<<<8, 256, 0, stream>>>(partials, partials, g1, be1, scsh);

    // --- layers 1..7 ---
    for (int l = 1; l < 8; ++l) {
        const ushort* Btl = Bt + (size_t)(l - 1) * DD * DD;
        gemm_bn_kernel<<<(NN + 63) / 64, 256, 0, stream>>>(Yb, Btl, scsh, Xb, NN);
        const float* b_l = (l <= 6) ? bm + (l - 1) * 256 : bl;
        int mode = (l < 7) ? 2 : 0;
        agg_kernel<<<NN / 4, 256, 0, stream>>>(
            Xb, Yb, OUT, rowptr, edges2, dinv, b_l, partials, mode);
        if (l < 7) {
            bn_finalize_kernel<<<8, 256, 0, stream>>>(
                partials, partials, gm + (l - 1) * 256, bem + (l - 1) * 256, scsh);
        }
    }
}